// Round 9
// baseline (260.868 us; speedup 1.0000x reference)
//
#include <hip/hip_runtime.h>
#include <hip/hip_bf16.h>

typedef __attribute__((ext_vector_type(8))) short short8;
typedef __attribute__((ext_vector_type(8))) unsigned short ushort8;
typedef __attribute__((ext_vector_type(4))) unsigned short bf16x4;
typedef __attribute__((ext_vector_type(4))) float f32x4;

#define BDIM 1024
#define SEQ  2048
#define NHD  16
#define NEGBIG (-1.0e30f)

__device__ __forceinline__ unsigned short f2bf(float x) {
  union { __hip_bfloat16 h; unsigned short u; } cv;
  cv.h = __float2bfloat16(x);
  return cv.u;
}

__device__ __forceinline__ void gload16(const void* g, void* l) {
  __builtin_amdgcn_global_load_lds((const __attribute__((address_space(1))) void*)g,
                                   (__attribute__((address_space(3))) void*)l, 16, 0, 0);
}

// ---------------- f32 -> bf16 conversion (X), 8 elems/lane ----------------
__global__ __launch_bounds__(256) void cvt_f32_bf16(const float* __restrict__ src,
                                                    unsigned short* __restrict__ dst) {
  int i = (blockIdx.x * 256 + threadIdx.x) * 8;
  float4 a = *(const float4*)(src + i);
  float4 b = *(const float4*)(src + i + 4);
  ushort8 o;
  o[0] = f2bf(a.x); o[1] = f2bf(a.y); o[2] = f2bf(a.z); o[3] = f2bf(a.w);
  o[4] = f2bf(b.x); o[5] = f2bf(b.y); o[6] = f2bf(b.z); o[7] = f2bf(b.w);
  *(ushort8*)(dst + i) = o;
}

// ---------------- weight transpose+convert: dst[n][k] = bf16(src[k][n]) ----------------
__global__ __launch_bounds__(256) void wtrans(const float* __restrict__ src,
                                              unsigned short* __restrict__ dst) {
  __shared__ float t[32][33];
  int tx = threadIdx.x, ty = threadIdx.y;
  int c0 = blockIdx.x * 32, r0 = blockIdx.y * 32;
  for (int i = ty; i < 32; i += 8)
    t[i][tx] = src[(size_t)(r0 + i) * BDIM + c0 + tx];
  __syncthreads();
  for (int i = ty; i < 32; i += 8)
    dst[(size_t)(c0 + i) * BDIM + r0 + tx] = f2bf(t[tx][i]);
}

// ---------------- GEMM: C[M][1024] = A[M][1024] * W, given WT[n][k] (bf16 in) --------
// tile 128x128, BK=64, 4 waves (2x2). Staging via global_load_lds width-16 with
// inverse-swizzled global source (verified: R2 gload == R3 reg-staged bit-identical).
template <bool F32OUT>
__global__ __launch_bounds__(256) void gemm_bt(const unsigned short* __restrict__ A,
                                               const unsigned short* __restrict__ BT,
                                               void* __restrict__ Cv) {
  __shared__ __align__(16) unsigned short As[128 * 64];
  __shared__ __align__(16) unsigned short Bs[128 * 64];
  const int tid = threadIdx.x;
  const int lane = tid & 63;
  const int w = tid >> 6;
  const int wr = w >> 1, wc = w & 1;
  const int m0 = blockIdx.x * 128;
  const int n0 = blockIdx.y * 128;
  const int l15 = lane & 15, lg = lane >> 4;

  f32x4 acc[4][4] = {};

  for (int k0 = 0; k0 < BDIM; k0 += 64) {
    for (int j = 0; j < 4; ++j) {
      int ob = (w * 4 + j) * 1024;
      int o = ob + lane * 16;
      int row = o >> 7;
      int kb = (o & 127) ^ ((row & 7) << 4);
      gload16(A + (size_t)(m0 + row) * BDIM + k0 + (kb >> 1), (char*)As + ob);
      gload16(BT + (size_t)(n0 + row) * BDIM + k0 + (kb >> 1), (char*)Bs + ob);
    }
    __syncthreads();
    for (int ks = 0; ks < 64; ks += 32) {
      int kb = (ks + lg * 8) * 2;
      short8 a[4], b[4];
      for (int mi = 0; mi < 4; ++mi) {
        int row = wr * 64 + mi * 16 + l15;
        a[mi] = *(const short8*)((const char*)As + row * 128 + (kb ^ ((row & 7) << 4)));
      }
      for (int nj = 0; nj < 4; ++nj) {
        int row = wc * 64 + nj * 16 + l15;
        b[nj] = *(const short8*)((const char*)Bs + row * 128 + (kb ^ ((row & 7) << 4)));
      }
      for (int mi = 0; mi < 4; ++mi)
        for (int nj = 0; nj < 4; ++nj)
          acc[mi][nj] = __builtin_amdgcn_mfma_f32_16x16x32_bf16(a[mi], b[nj], acc[mi][nj], 0, 0, 0);
    }
    __syncthreads();
  }
  for (int mi = 0; mi < 4; ++mi)
    for (int nj = 0; nj < 4; ++nj) {
      int m = m0 + wr * 64 + mi * 16 + lg * 4;
      int n = n0 + wc * 64 + nj * 16 + l15;
      for (int r = 0; r < 4; ++r) {
        if constexpr (F32OUT)
          ((float*)Cv)[(size_t)(m + r) * BDIM + n] = acc[mi][nj][r];
        else
          ((unsigned short*)Cv)[(size_t)(m + r) * BDIM + n] = f2bf(acc[mi][nj][r]);
      }
    }
}

// ---------------- flash attention (causal): swapped-MFMA, paired q-tiles, dbuf ----------
// block: q-tile pair (bx, 15-bx) -> uniform 34 kv-tiles. 4 waves x 32 q-rows.
// Pipeline: issue global K/V(t+1) -> compute(t) from LDS[cur] -> ds_write(t+1) -> barrier.
// Softmax: exp2-domain fma fold, diagonal-only masking, exact defer-max (sc==1 skip).
__global__ __launch_bounds__(256) void attn(const unsigned short* __restrict__ Qg,
                                            const unsigned short* __restrict__ Kg,
                                            const unsigned short* __restrict__ Vg,
                                            unsigned short* __restrict__ Og) {
  __shared__ __align__(16) unsigned short Ks[2][64 * 64];   // swz (row&7)<<4
  __shared__ __align__(16) unsigned short VTs[2][64 * 64];  // swzV ((d&7)^(d>>3))<<4
  __shared__ __align__(16) unsigned short Ps[128 * 64];     // swz (row&7)<<4

  const int tid = threadIdx.x;
  const int lane = tid & 63;
  const int w = tid >> 6;
  const int l15 = lane & 15, lg = lane >> 4;
  const int bh = blockIdx.y;
  const size_t base = ((size_t)(bh >> 4) * SEQ) * BDIM + (size_t)(bh & 15) * 64;
  constexpr float C = 0.125f * 1.44269504089f;  // log2(e) * (1/sqrt(64))

  // lane-invariant staging geometry
  int krow[2], kcol[2], kdst[2];
  for (int j = 0; j < 2; ++j) {
    int o = (w * 2 + j) * 1024 + lane * 16;
    int row = o >> 7, kb = o & 127;
    krow[j] = row; kcol[j] = kb >> 1;
    kdst[j] = row * 128 + (kb ^ ((row & 7) << 4));
  }
  const int vp = tid >> 3, vd8 = tid & 7;
  int vdst[8];
  for (int e = 0; e < 8; ++e) {
    int d = vd8 * 8 + e;
    vdst[e] = d * 128 + ((4 * vp) ^ ((((d & 7) ^ (d >> 3)) & 7) << 4));
  }

  for (int half = 0; half < 2; ++half) {
    const int qt = half == 0 ? (int)blockIdx.x : 15 - (int)blockIdx.x;
    const int q0 = qt * 128;

    // ---- stage Q tile transiently in Ps, pull frags ----
    for (int j = 0; j < 4; ++j) {
      int o = (w * 4 + j) * 1024 + lane * 16;
      int row = o >> 7, kb = o & 127;
      ushort8 qv = *(const ushort8*)(Qg + base + (size_t)(q0 + row) * BDIM + (kb >> 1));
      *(ushort8*)((char*)Ps + row * 128 + (kb ^ ((row & 7) << 4))) = qv;
    }
    __syncthreads();
    short8 qf[2][2];
    for (int mi = 0; mi < 2; ++mi)
      for (int ks = 0; ks < 2; ++ks) {
        int row = w * 32 + mi * 16 + l15;
        int kb = ks * 64 + lg * 16;
        qf[mi][ks] = *(const short8*)((const char*)Ps + row * 128 + (kb ^ ((row & 7) << 4)));
      }

    float mrow[2] = {NEGBIG, NEGBIG}, lrow[2] = {0.f, 0.f};
    f32x4 oacc[2][4] = {};  // [mi][di]: row d=di*16+4lg+r, col q=l15

    const int ntiles = qt * 2 + 2;

    // prologue: tile 0 -> regs -> LDS buf 0
    ushort8 kreg0, kreg1, vreg0, vreg1;
    {
      kreg0 = *(const ushort8*)(Kg + base + (size_t)(krow[0]) * BDIM + kcol[0]);
      kreg1 = *(const ushort8*)(Kg + base + (size_t)(krow[1]) * BDIM + kcol[1]);
      const unsigned short* vs = Vg + base + (size_t)(2 * vp) * BDIM + vd8 * 8;
      vreg0 = *(const ushort8*)vs;
      vreg1 = *(const ushort8*)(vs + BDIM);
      *(ushort8*)((char*)Ks[0] + kdst[0]) = kreg0;
      *(ushort8*)((char*)Ks[0] + kdst[1]) = kreg1;
      for (int e = 0; e < 8; ++e) {
        unsigned int pk = (unsigned int)vreg0[e] | ((unsigned int)vreg1[e] << 16);
        *(unsigned int*)((char*)VTs[0] + vdst[e]) = pk;
      }
    }
    __syncthreads();

    int cur = 0;
    for (int t = 0; t < ntiles; ++t) {
      const int kv0 = t * 64;
      const bool more = (t + 1 < ntiles);
      if (more) {  // issue next-tile global loads (latency hides under compute)
        const int nv0 = kv0 + 64;
        kreg0 = *(const ushort8*)(Kg + base + (size_t)(nv0 + krow[0]) * BDIM + kcol[0]);
        kreg1 = *(const ushort8*)(Kg + base + (size_t)(nv0 + krow[1]) * BDIM + kcol[1]);
        const unsigned short* vs = Vg + base + (size_t)(nv0 + 2 * vp) * BDIM + vd8 * 8;
        vreg0 = *(const ushort8*)vs;
        vreg1 = *(const ushort8*)(vs + BDIM);
      }

      if (kv0 <= q0 + w * 32 + 31) {  // wave-uniform causal skip
        // QK^T swapped -> s2[mi][kvj]: lane col q=l15, rows kv=kvj*16+4lg+r (raw scores)
        f32x4 s2[2][4];
        for (int kvj = 0; kvj < 4; ++kvj) {
          int row = kvj * 16 + l15;
          int sz = (row & 7) << 4;
          short8 kf0 = *(const short8*)((const char*)Ks[cur] + row * 128 + ((lg * 16) ^ sz));
          short8 kf1 = *(const short8*)((const char*)Ks[cur] + row * 128 + ((64 + lg * 16) ^ sz));
          for (int mi = 0; mi < 2; ++mi) {
            f32x4 z = {};
            z = __builtin_amdgcn_mfma_f32_16x16x32_bf16(kf0, qf[mi][0], z, 0, 0, 0);
            z = __builtin_amdgcn_mfma_f32_16x16x32_bf16(kf1, qf[mi][1], z, 0, 0, 0);
            s2[mi][kvj] = z;
          }
        }
        for (int mi = 0; mi < 2; ++mi) {
          const int qbase = q0 + w * 32 + mi * 16;
          const int qc = qbase + l15;
          float mx = NEGBIG;
          if (kv0 + 63 > qbase) {  // diagonal tile: apply causal mask
            for (int kvj = 0; kvj < 4; ++kvj)
              for (int r = 0; r < 4; ++r) {
                int kv = kv0 + kvj * 16 + 4 * lg + r;
                float v = s2[mi][kvj][r];
                if (kv > qc) { v = NEGBIG; s2[mi][kvj][r] = v; }
                mx = fmaxf(mx, v);
              }
          } else {  // interior tile: no masking
            for (int kvj = 0; kvj < 4; ++kvj)
              for (int r = 0; r < 4; ++r) mx = fmaxf(mx, s2[mi][kvj][r]);
          }
          mx = fmaxf(mx, __shfl_xor(mx, 16));
          mx = fmaxf(mx, __shfl_xor(mx, 32));
          if (!__all(mx <= mrow[mi])) {  // max grew somewhere: rescale (else sc==1 exactly)
            float mnew = fmaxf(mrow[mi], mx);
            float sc = exp2f((mrow[mi] - mnew) * C);
            mrow[mi] = mnew;
            lrow[mi] *= sc;
            for (int di = 0; di < 4; ++di)
              for (int r = 0; r < 4; ++r) oacc[mi][di][r] *= sc;
          }
          const float mC = mrow[mi] * C;
          float rs = 0.f;
          for (int kvj = 0; kvj < 4; ++kvj)
            for (int r = 0; r < 4; ++r) {
              float p = exp2f(fmaf(s2[mi][kvj][r], C, -mC));  // masked -> 0
              s2[mi][kvj][r] = p;
              rs += p;
            }
          rs += __shfl_xor(rs, 16);
          rs += __shfl_xor(rs, 32);
          lrow[mi] += rs;
          // P -> LDS (own wave's rows; b64 writes)
          int prow = w * 32 + mi * 16 + l15;
          int psz = (prow & 7) << 4;
          for (int kvj = 0; kvj < 4; ++kvj) {
            bf16x4 pk;
            pk[0] = f2bf(s2[mi][kvj][0]); pk[1] = f2bf(s2[mi][kvj][1]);
            pk[2] = f2bf(s2[mi][kvj][2]); pk[3] = f2bf(s2[mi][kvj][3]);
            *(bf16x4*)((char*)Ps + prow * 128 + ((kvj * 32 + lg * 8) ^ psz)) = pk;
          }
        }
        // PV swapped: oacc[mi][di] += mfma(VT-frag, P-frag) -> C[d][q]
        for (int ks = 0; ks < 2; ++ks) {
          short8 pa[2], vf[4];
          for (int mi = 0; mi < 2; ++mi) {
            int row = w * 32 + mi * 16 + l15;
            pa[mi] = *(const short8*)((const char*)Ps + row * 128 +
                                      ((ks * 64 + lg * 16) ^ ((row & 7) << 4)));
          }
          for (int di = 0; di < 4; ++di) {
            int d = di * 16 + l15;
            vf[di] = *(const short8*)((const char*)VTs[cur] + d * 128 +
                                      ((ks * 64 + lg * 16) ^ ((((d & 7) ^ (d >> 3)) & 7) << 4)));
          }
          for (int mi = 0; mi < 2; ++mi)
            for (int di = 0; di < 4; ++di)
              oacc[mi][di] = __builtin_amdgcn_mfma_f32_16x16x32_bf16(vf[di], pa[mi], oacc[mi][di], 0, 0, 0);
        }
      }

      if (more) {  // write next tile into the other buffer (no reader conflict)
        *(ushort8*)((char*)Ks[cur ^ 1] + kdst[0]) = kreg0;
        *(ushort8*)((char*)Ks[cur ^ 1] + kdst[1]) = kreg1;
        for (int e = 0; e < 8; ++e) {
          unsigned int pk = (unsigned int)vreg0[e] | ((unsigned int)vreg1[e] << 16);
          *(unsigned int*)((char*)VTs[cur ^ 1] + vdst[e]) = pk;
        }
      }
      __syncthreads();
      cur ^= 1;
    }

    // epilogue: lane col q, rows d=di*16+4lg+r -> b64 stores
    for (int mi = 0; mi < 2; ++mi) {
      float inv = 1.0f / lrow[mi];
      int qrow = q0 + w * 32 + mi * 16 + l15;
      for (int di = 0; di < 4; ++di) {
        bf16x4 ov;
        for (int r = 0; r < 4; ++r) ov[r] = f2bf(oacc[mi][di][r] * inv);
        *(bf16x4*)(Og + base + (size_t)qrow * BDIM + di * 16 + 4 * lg) = ov;
      }
    }
    __syncthreads();  // protect Ps before next half's Q staging
  }
}

extern "C" void kernel_launch(void* const* d_in, const int* in_sizes, int n_in,
                              void* d_out, int out_size, void* d_ws, size_t ws_size,
                              hipStream_t stream) {
  const float* X  = (const float*)d_in[0];
  const float* Wq = (const float*)d_in[1];
  const float* Wk = (const float*)d_in[2];
  const float* Wv = (const float*)d_in[3];
  const float* Wo = (const float*)d_in[4];

  const size_t WSZ = (size_t)1024 * 1024;
  const size_t MSZ = (size_t)8192 * 1024;
  const size_t need = (4 * WSZ + 4 * MSZ) * 2;  // 72 MB
  if (ws_size < need) return;

  unsigned short* ws = (unsigned short*)d_ws;
  unsigned short* WqT = ws;
  unsigned short* WkT = WqT + WSZ;
  unsigned short* WvT = WkT + WSZ;
  unsigned short* WoT = WvT + WSZ;
  unsigned short* Qw  = WoT + WSZ;
  unsigned short* Kw  = Qw + MSZ;
  unsigned short* Vw  = Kw + MSZ;
  unsigned short* Ow  = Vw + MSZ;
  unsigned short* Xb  = (unsigned short*)d_out;  // scratch; dead before final GEMM

  dim3 tb(32, 8);
  dim3 tg(32, 32);
  wtrans<<<tg, tb, 0, stream>>>(Wq, WqT);
  wtrans<<<tg, tb, 0, stream>>>(Wk, WkT);
  wtrans<<<tg, tb, 0, stream>>>(Wv, WvT);
  wtrans<<<tg, tb, 0, stream>>>(Wo, WoT);

  cvt_f32_bf16<<<(8192 * 1024) / (256 * 8), 256, 0, stream>>>(X, Xb);

  dim3 gg(64, 8);
  gemm_bt<false><<<gg, 256, 0, stream>>>(Xb, WqT, Qw);
  gemm_bt<false><<<gg, 256, 0, stream>>>(Xb, WkT, Kw);
  gemm_bt<false><<<gg, 256, 0, stream>>>(Xb, WvT, Vw);

  attn<<<dim3(8, 64), 256, 0, stream>>>(Qw, Kw, Vw, Ow);

  gemm_bt<true><<<gg, 256, 0, stream>>>(Ow, WoT, d_out);
}

// Round 10
// 204.596 us; speedup vs baseline: 1.2750x; 1.2750x over previous
//
#include <hip/hip_runtime.h>
#include <hip/hip_bf16.h>

typedef __attribute__((ext_vector_type(8))) short short8;
typedef __attribute__((ext_vector_type(8))) unsigned short ushort8;
typedef __attribute__((ext_vector_type(4))) unsigned short bf16x4;
typedef __attribute__((ext_vector_type(4))) float f32x4;

#define BDIM 1024
#define SEQ  2048
#define NHD  16
#define NEGBIG (-1.0e30f)

__device__ __forceinline__ unsigned short f2bf(float x) {
  union { __hip_bfloat16 h; unsigned short u; } cv;
  cv.h = __float2bfloat16(x);
  return cv.u;
}

__device__ __forceinline__ void gload16(const void* g, void* l) {
  __builtin_amdgcn_global_load_lds((const __attribute__((address_space(1))) void*)g,
                                   (__attribute__((address_space(3))) void*)l, 16, 0, 0);
}

// ---------------- f32 -> bf16 conversion (X), 8 elems/lane ----------------
__global__ __launch_bounds__(256) void cvt_f32_bf16(const float* __restrict__ src,
                                                    unsigned short* __restrict__ dst) {
  int i = (blockIdx.x * 256 + threadIdx.x) * 8;
  float4 a = *(const float4*)(src + i);
  float4 b = *(const float4*)(src + i + 4);
  ushort8 o;
  o[0] = f2bf(a.x); o[1] = f2bf(a.y); o[2] = f2bf(a.z); o[3] = f2bf(a.w);
  o[4] = f2bf(b.x); o[5] = f2bf(b.y); o[6] = f2bf(b.z); o[7] = f2bf(b.w);
  *(ushort8*)(dst + i) = o;
}

// ---------------- weight transpose+convert: dst[n][k] = bf16(src[k][n]) ----------------
__global__ __launch_bounds__(256) void wtrans(const float* __restrict__ src,
                                              unsigned short* __restrict__ dst) {
  __shared__ float t[32][33];
  int tx = threadIdx.x, ty = threadIdx.y;
  int c0 = blockIdx.x * 32, r0 = blockIdx.y * 32;
  for (int i = ty; i < 32; i += 8)
    t[i][tx] = src[(size_t)(r0 + i) * BDIM + c0 + tx];
  __syncthreads();
  for (int i = ty; i < 32; i += 8)
    dst[(size_t)(c0 + i) * BDIM + r0 + tx] = f2bf(t[tx][i]);
}

// ---------------- GEMM: C[M][1024] = A[M][1024] * W, given WT[n][k] (bf16 in) --------
// tile 128x128, BK=64, 4 waves (2x2). Staging via global_load_lds width-16 with
// inverse-swizzled global source (verified behaviorally identical to reg-staged).
template <bool F32OUT>
__global__ __launch_bounds__(256) void gemm_bt(const unsigned short* __restrict__ A,
                                               const unsigned short* __restrict__ BT,
                                               void* __restrict__ Cv) {
  __shared__ __align__(16) unsigned short As[128 * 64];
  __shared__ __align__(16) unsigned short Bs[128 * 64];
  const int tid = threadIdx.x;
  const int lane = tid & 63;
  const int w = tid >> 6;
  const int wr = w >> 1, wc = w & 1;
  const int m0 = blockIdx.x * 128;
  const int n0 = blockIdx.y * 128;
  const int l15 = lane & 15, lg = lane >> 4;

  f32x4 acc[4][4] = {};

  for (int k0 = 0; k0 < BDIM; k0 += 64) {
    for (int j = 0; j < 4; ++j) {
      int ob = (w * 4 + j) * 1024;
      int o = ob + lane * 16;
      int row = o >> 7;
      int kb = (o & 127) ^ ((row & 7) << 4);
      gload16(A + (size_t)(m0 + row) * BDIM + k0 + (kb >> 1), (char*)As + ob);
      gload16(BT + (size_t)(n0 + row) * BDIM + k0 + (kb >> 1), (char*)Bs + ob);
    }
    __syncthreads();
    for (int ks = 0; ks < 64; ks += 32) {
      int kb = (ks + lg * 8) * 2;
      short8 a[4], b[4];
      for (int mi = 0; mi < 4; ++mi) {
        int row = wr * 64 + mi * 16 + l15;
        a[mi] = *(const short8*)((const char*)As + row * 128 + (kb ^ ((row & 7) << 4)));
      }
      for (int nj = 0; nj < 4; ++nj) {
        int row = wc * 64 + nj * 16 + l15;
        b[nj] = *(const short8*)((const char*)Bs + row * 128 + (kb ^ ((row & 7) << 4)));
      }
      for (int mi = 0; mi < 4; ++mi)
        for (int nj = 0; nj < 4; ++nj)
          acc[mi][nj] = __builtin_amdgcn_mfma_f32_16x16x32_bf16(a[mi], b[nj], acc[mi][nj], 0, 0, 0);
    }
    __syncthreads();
  }
  for (int mi = 0; mi < 4; ++mi)
    for (int nj = 0; nj < 4; ++nj) {
      int m = m0 + wr * 64 + mi * 16 + lg * 4;
      int n = n0 + wc * 64 + nj * 16 + l15;
      for (int r = 0; r < 4; ++r) {
        if constexpr (F32OUT)
          ((float*)Cv)[(size_t)(m + r) * BDIM + n] = acc[mi][nj][r];
        else
          ((unsigned short*)Cv)[(size_t)(m + r) * BDIM + n] = f2bf(acc[mi][nj][r]);
      }
    }
}

// ---------------- flash attention (causal), swapped-MFMA + paired q-tiles ----------------
// R8 structure (two barriers/tile, 32KB LDS) + softmax diet:
//   exp2-domain (raw-score max; scale folded into C), __builtin_amdgcn_exp2f (v_exp_f32),
//   diagonal-only masking, exact defer-max (skip rescale when sc would be 1).
__global__ __launch_bounds__(256) void attn(const unsigned short* __restrict__ Qg,
                                            const unsigned short* __restrict__ Kg,
                                            const unsigned short* __restrict__ Vg,
                                            unsigned short* __restrict__ Og) {
  __shared__ __align__(16) unsigned short Sbuf[16384];  // 32 KB total
  unsigned short* Ks  = Sbuf;          // [64 kv][64 d]   swz (row&7)<<4
  unsigned short* VTs = Sbuf + 4096;   // [64 d][64 kv]   swzV ((d&7)^(d>>3))<<4
  unsigned short* Ps  = Sbuf + 8192;   // [128 q][64 kv]  swz (row&7)<<4

  const int tid = threadIdx.x;
  const int lane = tid & 63;
  const int w = tid >> 6;
  const int l15 = lane & 15, lg = lane >> 4;
  const int bh = blockIdx.y;
  const size_t base = ((size_t)(bh >> 4) * SEQ) * BDIM + (size_t)(bh & 15) * 64;
  constexpr float C = 0.125f * 1.44269504089f;  // (1/sqrt(64)) * log2(e)

  for (int half = 0; half < 2; ++half) {
    const int qt = half == 0 ? (int)blockIdx.x : 15 - (int)blockIdx.x;
    const int q0 = qt * 128;

    // ---- stage Q tile [128][64] transiently into Sbuf, pull frags, then reuse ----
    for (int j = 0; j < 4; ++j) {
      int o = (w * 4 + j) * 1024 + lane * 16;
      int row = o >> 7;
      int kb = o & 127;
      ushort8 qv = *(const ushort8*)(Qg + base + (size_t)(q0 + row) * BDIM + (kb >> 1));
      *(ushort8*)((char*)Sbuf + row * 128 + (kb ^ ((row & 7) << 4))) = qv;
    }
    __syncthreads();
    short8 qf[2][2];
    for (int mi = 0; mi < 2; ++mi)
      for (int ks = 0; ks < 2; ++ks) {
        int row = w * 32 + mi * 16 + l15;
        int kb = ks * 64 + lg * 16;
        qf[mi][ks] = *(const short8*)((const char*)Sbuf + row * 128 + (kb ^ ((row & 7) << 4)));
      }
    __syncthreads();  // Sbuf free for K/VT/P

    float mrow[2] = {NEGBIG, NEGBIG}, lrow[2] = {0.f, 0.f};
    f32x4 oacc[2][4] = {};  // [mi][di]: row d=di*16+4lg+r, col q=l15

    const int ntiles = qt * 2 + 2;
    for (int t = 0; t < ntiles; ++t) {
      const int kv0 = t * 64;
      // stage K [64][64] (b128 reg-staged, swizzled)
      for (int j = 0; j < 2; ++j) {
        int o = (w * 2 + j) * 1024 + lane * 16;
        int row = o >> 7;
        int kb = o & 127;
        ushort8 kv8 = *(const ushort8*)(Kg + base + (size_t)(kv0 + row) * BDIM + (kb >> 1));
        *(ushort8*)((char*)Ks + row * 128 + (kb ^ ((row & 7) << 4))) = kv8;
      }
      // stage V^T [d][kv]: kv-pair packed b32 writes, swzV
      {
        int p = tid >> 3, dc8 = tid & 7;
        const unsigned short* vs = Vg + base + (size_t)(kv0 + 2 * p) * BDIM + dc8 * 8;
        ushort8 v0 = *(const ushort8*)vs;
        ushort8 v1 = *(const ushort8*)(vs + BDIM);
        for (int e = 0; e < 8; ++e) {
          int d = dc8 * 8 + e;
          unsigned int pk = (unsigned int)v0[e] | ((unsigned int)v1[e] << 16);
          *(unsigned int*)((char*)VTs + d * 128 + ((4 * p) ^ ((((d & 7) ^ (d >> 3)) & 7) << 4))) = pk;
        }
      }
      __syncthreads();

      if (kv0 <= q0 + w * 32 + 31) {  // wave-uniform causal skip
        // QK^T swapped -> s2[mi][kvj]: lane col q=l15, rows kv=kvj*16+4lg+r (RAW scores)
        f32x4 s2[2][4];
        for (int kvj = 0; kvj < 4; ++kvj) {
          int row = kvj * 16 + l15;
          int sz = (row & 7) << 4;
          short8 kf0 = *(const short8*)((const char*)Ks + row * 128 + ((lg * 16) ^ sz));
          short8 kf1 = *(const short8*)((const char*)Ks + row * 128 + ((64 + lg * 16) ^ sz));
          for (int mi = 0; mi < 2; ++mi) {
            f32x4 z = {};
            z = __builtin_amdgcn_mfma_f32_16x16x32_bf16(kf0, qf[mi][0], z, 0, 0, 0);
            z = __builtin_amdgcn_mfma_f32_16x16x32_bf16(kf1, qf[mi][1], z, 0, 0, 0);
            s2[mi][kvj] = z;
          }
        }
        for (int mi = 0; mi < 2; ++mi) {
          const int qbase = q0 + w * 32 + mi * 16;
          const int qc = qbase + l15;
          float mx = NEGBIG;
          if (kv0 + 63 > qbase) {  // diagonal tile: apply causal mask
            for (int kvj = 0; kvj < 4; ++kvj)
              for (int r = 0; r < 4; ++r) {
                int kv = kv0 + kvj * 16 + 4 * lg + r;
                float v = s2[mi][kvj][r];
                if (kv > qc) { v = NEGBIG; s2[mi][kvj][r] = v; }
                mx = fmaxf(mx, v);
              }
          } else {  // interior tile: no masking needed
            for (int kvj = 0; kvj < 4; ++kvj)
              for (int r = 0; r < 4; ++r) mx = fmaxf(mx, s2[mi][kvj][r]);
          }
          mx = fmaxf(mx, __shfl_xor(mx, 16));
          mx = fmaxf(mx, __shfl_xor(mx, 32));
          if (!__all(mx <= mrow[mi])) {  // else sc==1 exactly: skip rescale
            float mnew = fmaxf(mrow[mi], mx);
            float sc = __builtin_amdgcn_exp2f((mrow[mi] - mnew) * C);
            mrow[mi] = mnew;
            lrow[mi] *= sc;
            for (int di = 0; di < 4; ++di)
              for (int r = 0; r < 4; ++r) oacc[mi][di][r] *= sc;
          }
          const float mC = mrow[mi] * C;
          float rs = 0.f;
          for (int kvj = 0; kvj < 4; ++kvj)
            for (int r = 0; r < 4; ++r) {
              float p = __builtin_amdgcn_exp2f(fmaf(s2[mi][kvj][r], C, -mC));  // masked -> 0
              s2[mi][kvj][r] = p;
              rs += p;
            }
          rs += __shfl_xor(rs, 16);
          rs += __shfl_xor(rs, 32);
          lrow[mi] += rs;
          // P -> LDS: lane's 4 consecutive kv per kvj = one b64 write (own rows only)
          int prow = w * 32 + mi * 16 + l15;
          int psz = (prow & 7) << 4;
          for (int kvj = 0; kvj < 4; ++kvj) {
            bf16x4 pk;
            pk[0] = f2bf(s2[mi][kvj][0]); pk[1] = f2bf(s2[mi][kvj][1]);
            pk[2] = f2bf(s2[mi][kvj][2]); pk[3] = f2bf(s2[mi][kvj][3]);
            *(bf16x4*)((char*)Ps + prow * 128 + ((kvj * 32 + lg * 8) ^ psz)) = pk;
          }
        }
        // PV swapped: oacc[mi][di] += mfma(VT-frag, P-frag) -> C[d][q]
        for (int ks = 0; ks < 2; ++ks) {
          short8 pa[2], vf[4];
          for (int mi = 0; mi < 2; ++mi) {
            int row = w * 32 + mi * 16 + l15;
            pa[mi] = *(const short8*)((const char*)Ps + row * 128 +
                                      ((ks * 64 + lg * 16) ^ ((row & 7) << 4)));
          }
          for (int di = 0; di < 4; ++di) {
            int d = di * 16 + l15;
            vf[di] = *(const short8*)((const char*)VTs + d * 128 +
                                      ((ks * 64 + lg * 16) ^ ((((d & 7) ^ (d >> 3)) & 7) << 4)));
          }
          for (int mi = 0; mi < 2; ++mi)
            for (int di = 0; di < 4; ++di)
              oacc[mi][di] = __builtin_amdgcn_mfma_f32_16x16x32_bf16(vf[di], pa[mi], oacc[mi][di], 0, 0, 0);
        }
      }
      __syncthreads();
    }

    // epilogue: lane col q, rows d=di*16+4lg+r -> 4 consecutive d = b64 stores
    for (int mi = 0; mi < 2; ++mi) {
      float inv = 1.0f / lrow[mi];
      int qrow = q0 + w * 32 + mi * 16 + l15;
      for (int di = 0; di < 4; ++di) {
        bf16x4 ov;
        for (int r = 0; r < 4; ++r) ov[r] = f2bf(oacc[mi][di][r] * inv);
        *(bf16x4*)(Og + base + (size_t)qrow * BDIM + di * 16 + 4 * lg) = ov;
      }
    }
  }
}

extern "C" void kernel_launch(void* const* d_in, const int* in_sizes, int n_in,
                              void* d_out, int out_size, void* d_ws, size_t ws_size,
                              hipStream_t stream) {
  const float* X  = (const float*)d_in[0];
  const float* Wq = (const float*)d_in[1];
  const float* Wk = (const float*)d_in[2];
  const float* Wv = (const float*)d_in[3];
  const float* Wo = (const float*)d_in[4];

  const size_t WSZ = (size_t)1024 * 1024;
  const size_t MSZ = (size_t)8192 * 1024;
  const size_t need = (4 * WSZ + 4 * MSZ) * 2;  // 72 MB
  if (ws_size < need) return;

  unsigned short* ws = (unsigned short*)d_ws;
  unsigned short* WqT = ws;
  unsigned short* WkT = WqT + WSZ;
  unsigned short* WvT = WkT + WSZ;
  unsigned short* WoT = WvT + WSZ;
  unsigned short* Qw  = WoT + WSZ;
  unsigned short* Kw  = Qw + MSZ;
  unsigned short* Vw  = Kw + MSZ;
  unsigned short* Ow  = Vw + MSZ;
  unsigned short* Xb  = (unsigned short*)d_out;  // scratch; dead before final GEMM

  dim3 tb(32, 8);
  dim3 tg(32, 32);
  wtrans<<<tg, tb, 0, stream>>>(Wq, WqT);
  wtrans<<<tg, tb, 0, stream>>>(Wk, WkT);
  wtrans<<<tg, tb, 0, stream>>>(Wv, WvT);
  wtrans<<<tg, tb, 0, stream>>>(Wo, WoT);

  cvt_f32_bf16<<<(8192 * 1024) / (256 * 8), 256, 0, stream>>>(X, Xb);

  dim3 gg(64, 8);
  gemm_bt<false><<<gg, 256, 0, stream>>>(Xb, WqT, Qw);
  gemm_bt<false><<<gg, 256, 0, stream>>>(Xb, WkT, Kw);
  gemm_bt<false><<<gg, 256, 0, stream>>>(Xb, WvT, Vw);

  attn<<<dim3(8, 64), 256, 0, stream>>>(Qw, Kw, Vw, Ow);

  gemm_bt<true><<<gg, 256, 0, stream>>>(Ow, WoT, d_out);
}